// Round 1
// baseline (336.656 us; speedup 1.0000x reference)
//
#include <hip/hip_runtime.h>
#include <hip/hip_bf16.h>
#include <stdint.h>

#define NN 8192
#define IN_DIM 343
#define IN_PAD 352
#define HID 1000
#define HID_PAD 1024
#define EPS 1e-5f

typedef __attribute__((ext_vector_type(8))) short bf16x8;
typedef __attribute__((ext_vector_type(4))) float f32x4;

static __device__ __forceinline__ unsigned short f2bf(float f) {
    union { float f; unsigned int u; } v; v.f = f;
    unsigned int u = v.u;
    unsigned int r = (u + 0x7FFFu + ((u >> 16) & 1u)) >> 16;   // RNE
    return (unsigned short)r;
}

// ---------------- conversion kernels ----------------

__global__ __launch_bounds__(256) void k_cvt_adj(const float* __restrict__ src,
                                                 unsigned short* __restrict__ dst, int n8) {
    int i = blockIdx.x * blockDim.x + threadIdx.x;
    int stride = gridDim.x * blockDim.x;
    for (; i < n8; i += stride) {
        const float4* s = (const float4*)(src + (size_t)i * 8);
        float4 a = s[0], b = s[1];
        uint4 o;
        o.x = (unsigned)f2bf(a.x) | ((unsigned)f2bf(a.y) << 16);
        o.y = (unsigned)f2bf(a.z) | ((unsigned)f2bf(a.w) << 16);
        o.z = (unsigned)f2bf(b.x) | ((unsigned)f2bf(b.y) << 16);
        o.w = (unsigned)f2bf(b.z) | ((unsigned)f2bf(b.w) << 16);
        *(uint4*)(dst + (size_t)i * 8) = o;
    }
}

// features [8192][343] fp32 -> feat_p [8192][352] bf16 (zero pad)
__global__ __launch_bounds__(256) void k_cvt_feat(const float* __restrict__ src,
                                                  unsigned short* __restrict__ dst) {
    int idx = blockIdx.x * blockDim.x + threadIdx.x;
    if (idx >= NN * IN_PAD) return;
    int row = idx / IN_PAD;
    int col = idx - row * IN_PAD;
    dst[idx] = (col < IN_DIM) ? f2bf(src[(size_t)row * IN_DIM + col]) : 0;
}

// W1 [343][1000] fp32 -> w1t [1024][352] bf16 (transposed, zero pad)
__global__ __launch_bounds__(256) void k_cvt_w1t(const float* __restrict__ W1,
                                                 unsigned short* __restrict__ dst) {
    int idx = blockIdx.x * blockDim.x + threadIdx.x;
    if (idx >= HID_PAD * IN_PAD) return;
    int n = idx / IN_PAD;
    int k = idx - n * IN_PAD;
    dst[idx] = (k < IN_DIM && n < HID) ? f2bf(W1[(size_t)k * HID + n]) : 0;
}

// ---------------- GEMM: C[M][N] = A[M][K] * Bt[N][K]^T ----------------
// 128x128 tile, BK=32, 4 waves (2x2), 16x16x32 bf16 MFMA, global_load_lds staging.
// EPI==0: store bf16 C.  EPI==1: store fp32 relu(C + bias[col]).

template <int EPI>
__global__ void k_gemm(const unsigned short* __restrict__ A,
                       const unsigned short* __restrict__ Bt,
                       void* __restrict__ Cout,
                       const float* __restrict__ bias,
                       int M, int N, int K) {
    __shared__ unsigned short ldsA[128 * 32];
    __shared__ unsigned short ldsB[128 * 32];

    const int tid = threadIdx.x;
    const int nbn = N >> 7;
    const int bm = blockIdx.x / nbn;
    const int bn = blockIdx.x - bm * nbn;

    const int wid = tid >> 6, lane = tid & 63;
    const int wr = wid >> 1, wc = wid & 1;
    const int lr = lane & 15, lg = lane >> 4;

    f32x4 acc[4][4] = {};

    // staging: chunk c = issue*256 + tid ; row = c>>2 ; seg = c&3 (16B = 8 bf16 per chunk)
    const int r0 = tid >> 2, s0 = tid & 3;
    const unsigned short* Ag0 = A + ((size_t)bm * 128 + r0) * K + s0 * 8;
    const unsigned short* Ag1 = A + ((size_t)bm * 128 + 64 + r0) * K + s0 * 8;
    const unsigned short* Bg0 = Bt + ((size_t)bn * 128 + r0) * K + s0 * 8;
    const unsigned short* Bg1 = Bt + ((size_t)bn * 128 + 64 + r0) * K + s0 * 8;
    // wave-uniform LDS bases (lane writes base + lane*16)
    unsigned short* lA0 = ldsA + (size_t)(wid * 64) * 8;
    unsigned short* lA1 = ldsA + (size_t)(256 + wid * 64) * 8;
    unsigned short* lB0 = ldsB + (size_t)(wid * 64) * 8;
    unsigned short* lB1 = ldsB + (size_t)(256 + wid * 64) * 8;

    for (int kt = 0; kt < K; kt += 32) {
        __builtin_amdgcn_global_load_lds(
            (const __attribute__((address_space(1))) void*)(Ag0 + kt),
            (__attribute__((address_space(3))) void*)lA0, 16, 0, 0);
        __builtin_amdgcn_global_load_lds(
            (const __attribute__((address_space(1))) void*)(Ag1 + kt),
            (__attribute__((address_space(3))) void*)lA1, 16, 0, 0);
        __builtin_amdgcn_global_load_lds(
            (const __attribute__((address_space(1))) void*)(Bg0 + kt),
            (__attribute__((address_space(3))) void*)lB0, 16, 0, 0);
        __builtin_amdgcn_global_load_lds(
            (const __attribute__((address_space(1))) void*)(Bg1 + kt),
            (__attribute__((address_space(3))) void*)lB1, 16, 0, 0);
        __syncthreads();   // drains vmcnt; LDS tiles ready

        bf16x8 af[4], bfr[4];
#pragma unroll
        for (int i = 0; i < 4; i++) {
            af[i]  = *(const bf16x8*)&ldsA[((wr * 64 + i * 16 + lr) * 32) + lg * 8];
            bfr[i] = *(const bf16x8*)&ldsB[((wc * 64 + i * 16 + lr) * 32) + lg * 8];
        }
#pragma unroll
        for (int i = 0; i < 4; i++)
#pragma unroll
            for (int j = 0; j < 4; j++)
                acc[i][j] = __builtin_amdgcn_mfma_f32_16x16x32_bf16(af[i], bfr[j], acc[i][j], 0, 0, 0);
        __syncthreads();   // all waves done reading before next stage
    }

    // epilogue: C row = (lane>>4)*4 + reg, col = lane&15 within each 16x16 frag
    const int row0 = bm * 128 + wr * 64;
    const int col0 = bn * 128 + wc * 64;
#pragma unroll
    for (int mi = 0; mi < 4; mi++) {
#pragma unroll
        for (int ni = 0; ni < 4; ni++) {
            int col = col0 + ni * 16 + lr;
#pragma unroll
            for (int j = 0; j < 4; j++) {
                int row = row0 + mi * 16 + lg * 4 + j;
                float v = acc[mi][ni][j];
                if (EPI == 0) {
                    ((unsigned short*)Cout)[(size_t)row * N + col] = f2bf(v);
                } else {
                    float b = (col < HID) ? bias[col] : 0.f;
                    v += b;
                    v = v > 0.f ? v : 0.f;
                    ((float*)Cout)[(size_t)row * N + col] = v;
                }
            }
        }
    }
}

// ---------------- LayerNorm + head, one row per block ----------------
__global__ __launch_bounds__(256) void k_ln_head(const float* __restrict__ h1,
                                                 const float* __restrict__ gamma,
                                                 const float* __restrict__ beta,
                                                 const float* __restrict__ Wm,
                                                 const float* __restrict__ bm,
                                                 float* __restrict__ out) {
    const int row = blockIdx.x;
    const int t = threadIdx.x;
    const float* hr = h1 + (size_t)row * HID_PAD;

    float v[4];
    float s = 0.f, ss = 0.f;
#pragma unroll
    for (int i = 0; i < 4; i++) {
        int ix = t + i * 256;
        float x = (ix < HID) ? hr[ix] : 0.f;
        v[i] = x; s += x; ss += x * x;
    }
#pragma unroll
    for (int o = 32; o > 0; o >>= 1) { s += __shfl_down(s, o); ss += __shfl_down(ss, o); }

    __shared__ float rs[8], rss[8];
    const int wid = t >> 6, lane = t & 63;
    if (lane == 0) { rs[wid] = s; rss[wid] = ss; }
    __syncthreads();
    if (t == 0) {
        float a = 0.f, b = 0.f;
        for (int w = 0; w < 4; w++) { a += rs[w]; b += rss[w]; }
        rs[4] = a; rss[4] = b;
    }
    __syncthreads();
    const float mean = rs[4] * (1.0f / HID);
    const float var = rss[4] * (1.0f / HID) - mean * mean;
    const float rstd = rsqrtf(var + EPS);

    float p0 = 0.f, p1 = 0.f, p2 = 0.f, p3 = 0.f;
#pragma unroll
    for (int i = 0; i < 4; i++) {
        int ix = t + i * 256;
        if (ix < HID) {
            float hn = (v[i] - mean) * rstd * gamma[ix] + beta[ix];
            const float* w = Wm + (size_t)ix * 4;
            p0 += hn * w[0]; p1 += hn * w[1]; p2 += hn * w[2]; p3 += hn * w[3];
        }
    }
#pragma unroll
    for (int o = 32; o > 0; o >>= 1) {
        p0 += __shfl_down(p0, o); p1 += __shfl_down(p1, o);
        p2 += __shfl_down(p2, o); p3 += __shfl_down(p3, o);
    }
    __shared__ float rp[4][4];
    if (lane == 0) { rp[wid][0] = p0; rp[wid][1] = p1; rp[wid][2] = p2; rp[wid][3] = p3; }
    __syncthreads();
    if (t < 4) {
        float a = rp[0][t] + rp[1][t] + rp[2][t] + rp[3][t] + bm[t];
        out[(size_t)row * 4 + t] = a;
    }
}

// ---------------- launcher ----------------
extern "C" void kernel_launch(void* const* d_in, const int* in_sizes, int n_in,
                              void* d_out, int out_size, void* d_ws, size_t ws_size,
                              hipStream_t stream) {
    const float* adj      = (const float*)d_in[0];   // [8192][8192]
    const float* features = (const float*)d_in[1];   // [8192][343]
    const float* W1       = (const float*)d_in[2];   // [343][1000]
    const float* b1       = (const float*)d_in[3];   // [1000]
    const float* gamma    = (const float*)d_in[4];   // [1000]
    const float* beta     = (const float*)d_in[5];   // [1000]
    const float* Wm       = (const float*)d_in[6];   // [1000][4]
    const float* bm       = (const float*)d_in[7];   // [4]
    float* out = (float*)d_out;

    uint8_t* ws = (uint8_t*)d_ws;
    unsigned short* adj_bf = (unsigned short*)ws;                       // 134,217,728 B
    unsigned short* feat_p = (unsigned short*)(ws + 134217728);         //   5,767,168 B
    unsigned short* w1t    = (unsigned short*)(ws + 139984896);         //     720,896 B
    unsigned short* xwt    = (unsigned short*)(ws + 140705792);         //  16,777,216 B
    float*          h1     = (float*)(ws + 157483008);                  //  33,554,432 B  (total ~191 MB)

    k_cvt_adj<<<2048, 256, 0, stream>>>(adj, adj_bf, NN * NN / 8);
    k_cvt_feat<<<(NN * IN_PAD + 255) / 256, 256, 0, stream>>>(features, feat_p);
    k_cvt_w1t<<<(HID_PAD * IN_PAD + 255) / 256, 256, 0, stream>>>(W1, w1t);

    // GEMM1: xwt[1024][8192] = w1t[1024][352] * feat_p[8192][352]^T   (bf16 out)
    k_gemm<0><<<(HID_PAD / 128) * (NN / 128), 256, 0, stream>>>(
        w1t, feat_p, (void*)xwt, nullptr, HID_PAD, NN, IN_PAD);

    // GEMM2: h1[8192][1024] = relu(adj_bf[8192][8192] * xwt[1024][8192]^T + b1)  (fp32 out)
    k_gemm<1><<<(NN / 128) * (HID_PAD / 128), 256, 0, stream>>>(
        adj_bf, xwt, (void*)h1, b1, NN, HID_PAD, NN);

    k_ln_head<<<NN, 256, 0, stream>>>(h1, gamma, beta, Wm, bm, out);
}

// Round 2
// 332.818 us; speedup vs baseline: 1.0115x; 1.0115x over previous
//
#include <hip/hip_runtime.h>
#include <hip/hip_bf16.h>
#include <stdint.h>

#define NN 8192
#define IN_DIM 343
#define IN_PAD 352
#define HID 1000
#define HID_PAD 1024
#define EPS 1e-5f

typedef __attribute__((ext_vector_type(8))) short bf16x8;
typedef __attribute__((ext_vector_type(4))) float f32x4;

static __device__ __forceinline__ unsigned short f2bf(float f) {
    union { float f; unsigned int u; } v; v.f = f;
    unsigned int u = v.u;
    unsigned int r = (u + 0x7FFFu + ((u >> 16) & 1u)) >> 16;   // RNE
    return (unsigned short)r;
}

// packed RNE f32x2 -> bf16x2 (no builtin on gfx950; single VALU op)
static __device__ __forceinline__ unsigned cvt_pk_bf16(float lo, float hi) {
    unsigned r;
    asm("v_cvt_pk_bf16_f32 %0, %1, %2" : "=v"(r) : "v"(lo), "v"(hi));
    return r;
}

// ---------------- conversion kernels (small) ----------------

// features [8192][343] fp32 -> feat_p [8192][352] bf16 (zero pad)
__global__ __launch_bounds__(256) void k_cvt_feat(const float* __restrict__ src,
                                                  unsigned short* __restrict__ dst) {
    int idx = blockIdx.x * blockDim.x + threadIdx.x;
    if (idx >= NN * IN_PAD) return;
    int row = idx / IN_PAD;
    int col = idx - row * IN_PAD;
    dst[idx] = (col < IN_DIM) ? f2bf(src[(size_t)row * IN_DIM + col]) : 0;
}

// W1 [343][1000] fp32 -> w1t [1024][352] bf16 (transposed, zero pad)
__global__ __launch_bounds__(256) void k_cvt_w1t(const float* __restrict__ W1,
                                                 unsigned short* __restrict__ dst) {
    int idx = blockIdx.x * blockDim.x + threadIdx.x;
    if (idx >= HID_PAD * IN_PAD) return;
    int n = idx / IN_PAD;
    int k = idx - n * IN_PAD;
    dst[idx] = (k < IN_DIM && n < HID) ? f2bf(W1[(size_t)k * HID + n]) : 0;
}

// ---------------- GEMM1: C[M][N] = A[M][K] * Bt[N][K]^T  (bf16 in, bf16 out) ----------------
// 128x128 tile, BK=32, 4 waves (2x2), 16x16x32 bf16 MFMA, global_load_lds staging.

__global__ void k_gemm_bf(const unsigned short* __restrict__ A,
                          const unsigned short* __restrict__ Bt,
                          unsigned short* __restrict__ Cout,
                          int M, int N, int K) {
    __shared__ unsigned short ldsA[128 * 32];
    __shared__ unsigned short ldsB[128 * 32];

    const int tid = threadIdx.x;
    const int nbn = N >> 7;
    const int bm = blockIdx.x / nbn;
    const int bn = blockIdx.x - bm * nbn;

    const int wid = tid >> 6, lane = tid & 63;
    const int wr = wid >> 1, wc = wid & 1;
    const int lr = lane & 15, lg = lane >> 4;

    f32x4 acc[4][4] = {};

    const int r0 = tid >> 2, s0 = tid & 3;
    const unsigned short* Ag0 = A + ((size_t)bm * 128 + r0) * K + s0 * 8;
    const unsigned short* Ag1 = A + ((size_t)bm * 128 + 64 + r0) * K + s0 * 8;
    const unsigned short* Bg0 = Bt + ((size_t)bn * 128 + r0) * K + s0 * 8;
    const unsigned short* Bg1 = Bt + ((size_t)bn * 128 + 64 + r0) * K + s0 * 8;
    unsigned short* lA0 = ldsA + (size_t)(wid * 64) * 8;
    unsigned short* lA1 = ldsA + (size_t)(256 + wid * 64) * 8;
    unsigned short* lB0 = ldsB + (size_t)(wid * 64) * 8;
    unsigned short* lB1 = ldsB + (size_t)(256 + wid * 64) * 8;

    for (int kt = 0; kt < K; kt += 32) {
        __builtin_amdgcn_global_load_lds(
            (const __attribute__((address_space(1))) void*)(Ag0 + kt),
            (__attribute__((address_space(3))) void*)lA0, 16, 0, 0);
        __builtin_amdgcn_global_load_lds(
            (const __attribute__((address_space(1))) void*)(Ag1 + kt),
            (__attribute__((address_space(3))) void*)lA1, 16, 0, 0);
        __builtin_amdgcn_global_load_lds(
            (const __attribute__((address_space(1))) void*)(Bg0 + kt),
            (__attribute__((address_space(3))) void*)lB0, 16, 0, 0);
        __builtin_amdgcn_global_load_lds(
            (const __attribute__((address_space(1))) void*)(Bg1 + kt),
            (__attribute__((address_space(3))) void*)lB1, 16, 0, 0);
        __syncthreads();

        bf16x8 af[4], bfr[4];
#pragma unroll
        for (int i = 0; i < 4; i++) {
            af[i]  = *(const bf16x8*)&ldsA[((wr * 64 + i * 16 + lr) * 32) + lg * 8];
            bfr[i] = *(const bf16x8*)&ldsB[((wc * 64 + i * 16 + lr) * 32) + lg * 8];
        }
#pragma unroll
        for (int i = 0; i < 4; i++)
#pragma unroll
            for (int j = 0; j < 4; j++)
                acc[i][j] = __builtin_amdgcn_mfma_f32_16x16x32_bf16(af[i], bfr[j], acc[i][j], 0, 0, 0);
        __syncthreads();
    }

    const int row0 = bm * 128 + wr * 64;
    const int col0 = bn * 128 + wc * 64;
#pragma unroll
    for (int mi = 0; mi < 4; mi++) {
#pragma unroll
        for (int ni = 0; ni < 4; ni++) {
            int col = col0 + ni * 16 + lr;
#pragma unroll
            for (int j = 0; j < 4; j++) {
                int row = row0 + mi * 16 + lg * 4 + j;
                Cout[(size_t)row * N + col] = f2bf(acc[mi][ni][j]);
            }
        }
    }
}

// ---------------- GEMM2 fused: h1 = relu(adj_f32 * xwt^T + b1) ----------------
// A = adj fp32 [8192][8192] converted to bf16 on the fly (reg-staged, pk-cvt, ds_write).
// B = xwt bf16 [1024][8192] via global_load_lds.
// XCD-bijective swizzle: all 8 bn-blocks of a bm land on one XCD -> adj fetched ~once.

__global__ __launch_bounds__(256) void k_gemm2_fused(const float* __restrict__ A,
                                                     const unsigned short* __restrict__ Bt,
                                                     float* __restrict__ C,
                                                     const float* __restrict__ bias) {
    __shared__ unsigned short ldsA[128 * 32];
    __shared__ unsigned short ldsB[128 * 32];

    const int tid = threadIdx.x;
    // 512 blocks, 8 XCDs, 64 blocks/XCD. XCD x gets bm in [x*8, x*8+8), all bn.
    const int wg = blockIdx.x;
    const int swz = (wg & 7) * 64 + (wg >> 3);
    const int bm = swz >> 3;      // 0..63
    const int bn = swz & 7;       // 0..7

    const int wid = tid >> 6, lane = tid & 63;
    const int wr = wid >> 1, wc = wid & 1;
    const int lr = lane & 15, lg = lane >> 4;

    f32x4 acc[4][4] = {};

    // ---- A staging geometry (fp32 -> bf16): thread loads 4x float4 per K-step
    const int ar = tid >> 3;       // 0..31: row within 32-row group
    const int as = tid & 7;        // 0..7 : 4-col segment
    const float* Ag = A + ((size_t)bm * 128 + ar) * NN + as * 4;

    // ---- B staging geometry (global_load_lds, 16B/lane)
    const int r0 = tid >> 2, s0 = tid & 3;
    const unsigned short* Bg0 = Bt + ((size_t)bn * 128 + r0) * NN + s0 * 8;
    const unsigned short* Bg1 = Bt + ((size_t)bn * 128 + 64 + r0) * NN + s0 * 8;
    unsigned short* lB0 = ldsB + (size_t)(wid * 64) * 8;
    unsigned short* lB1 = ldsB + (size_t)(256 + wid * 64) * 8;

    // prologue: load A(kt=0) into regs
    float4 areg[4];
#pragma unroll
    for (int j = 0; j < 4; j++)
        areg[j] = *(const float4*)(Ag + (size_t)j * 32 * NN);

    for (int kt = 0; kt < NN; kt += 32) {
        // issue B stage first (latency overlaps A cvt+write VALU work)
        __builtin_amdgcn_global_load_lds(
            (const __attribute__((address_space(1))) void*)(Bg0 + kt),
            (__attribute__((address_space(3))) void*)lB0, 16, 0, 0);
        __builtin_amdgcn_global_load_lds(
            (const __attribute__((address_space(1))) void*)(Bg1 + kt),
            (__attribute__((address_space(3))) void*)lB1, 16, 0, 0);

        // A: cvt fp32->bf16 packed, write 8B/chunk to LDS
#pragma unroll
        for (int j = 0; j < 4; j++) {
            uint2 pk;
            pk.x = cvt_pk_bf16(areg[j].x, areg[j].y);
            pk.y = cvt_pk_bf16(areg[j].z, areg[j].w);
            *(uint2*)&ldsA[(j * 32 + ar) * 32 + as * 4] = pk;
        }
        __syncthreads();   // B gload + A ds_writes drained; tiles ready

        // prefetch next A tile (in flight across the MFMA phase)
        const int kn = (kt + 32 < NN) ? kt + 32 : kt;   // clamp; last-iter reload unused
#pragma unroll
        for (int j = 0; j < 4; j++)
            areg[j] = *(const float4*)(Ag + (size_t)j * 32 * NN + kn);

        bf16x8 af[4], bfr[4];
#pragma unroll
        for (int i = 0; i < 4; i++) {
            af[i]  = *(const bf16x8*)&ldsA[((wr * 64 + i * 16 + lr) * 32) + lg * 8];
            bfr[i] = *(const bf16x8*)&ldsB[((wc * 64 + i * 16 + lr) * 32) + lg * 8];
        }
#pragma unroll
        for (int i = 0; i < 4; i++)
#pragma unroll
            for (int j = 0; j < 4; j++)
                acc[i][j] = __builtin_amdgcn_mfma_f32_16x16x32_bf16(af[i], bfr[j], acc[i][j], 0, 0, 0);
        __syncthreads();
    }

    // epilogue: relu(acc + bias), fp32 store. C row=(lane>>4)*4+reg, col=lane&15.
    const int row0 = bm * 128 + wr * 64;
    const int col0 = bn * 128 + wc * 64;
#pragma unroll
    for (int mi = 0; mi < 4; mi++) {
#pragma unroll
        for (int ni = 0; ni < 4; ni++) {
            int col = col0 + ni * 16 + lr;
            float b = (col < HID) ? bias[col] : 0.f;
#pragma unroll
            for (int j = 0; j < 4; j++) {
                int row = row0 + mi * 16 + lg * 4 + j;
                float v = acc[mi][ni][j] + b;
                v = v > 0.f ? v : 0.f;
                C[(size_t)row * HID_PAD + col] = v;
            }
        }
    }
}

// ---------------- LayerNorm + head, one row per block ----------------
__global__ __launch_bounds__(256) void k_ln_head(const float* __restrict__ h1,
                                                 const float* __restrict__ gamma,
                                                 const float* __restrict__ beta,
                                                 const float* __restrict__ Wm,
                                                 const float* __restrict__ bm,
                                                 float* __restrict__ out) {
    const int row = blockIdx.x;
    const int t = threadIdx.x;
    const float* hr = h1 + (size_t)row * HID_PAD;

    float v[4];
    float s = 0.f, ss = 0.f;
#pragma unroll
    for (int i = 0; i < 4; i++) {
        int ix = t + i * 256;
        float x = (ix < HID) ? hr[ix] : 0.f;
        v[i] = x; s += x; ss += x * x;
    }
#pragma unroll
    for (int o = 32; o > 0; o >>= 1) { s += __shfl_down(s, o); ss += __shfl_down(ss, o); }

    __shared__ float rs[8], rss[8];
    const int wid = t >> 6, lane = t & 63;
    if (lane == 0) { rs[wid] = s; rss[wid] = ss; }
    __syncthreads();
    if (t == 0) {
        float a = 0.f, b = 0.f;
        for (int w = 0; w < 4; w++) { a += rs[w]; b += rss[w]; }
        rs[4] = a; rss[4] = b;
    }
    __syncthreads();
    const float mean = rs[4] * (1.0f / HID);
    const float var = rss[4] * (1.0f / HID) - mean * mean;
    const float rstd = rsqrtf(var + EPS);

    float p0 = 0.f, p1 = 0.f, p2 = 0.f, p3 = 0.f;
#pragma unroll
    for (int i = 0; i < 4; i++) {
        int ix = t + i * 256;
        if (ix < HID) {
            float hn = (v[i] - mean) * rstd * gamma[ix] + beta[ix];
            const float* w = Wm + (size_t)ix * 4;
            p0 += hn * w[0]; p1 += hn * w[1]; p2 += hn * w[2]; p3 += hn * w[3];
        }
    }
#pragma unroll
    for (int o = 32; o > 0; o >>= 1) {
        p0 += __shfl_down(p0, o); p1 += __shfl_down(p1, o);
        p2 += __shfl_down(p2, o); p3 += __shfl_down(p3, o);
    }
    __shared__ float rp[4][4];
    if (lane == 0) { rp[wid][0] = p0; rp[wid][1] = p1; rp[wid][2] = p2; rp[wid][3] = p3; }
    __syncthreads();
    if (t < 4) {
        float a = rp[0][t] + rp[1][t] + rp[2][t] + rp[3][t] + bm[t];
        out[(size_t)row * 4 + t] = a;
    }
}

// ---------------- launcher ----------------
extern "C" void kernel_launch(void* const* d_in, const int* in_sizes, int n_in,
                              void* d_out, int out_size, void* d_ws, size_t ws_size,
                              hipStream_t stream) {
    const float* adj      = (const float*)d_in[0];   // [8192][8192]
    const float* features = (const float*)d_in[1];   // [8192][343]
    const float* W1       = (const float*)d_in[2];   // [343][1000]
    const float* b1       = (const float*)d_in[3];   // [1000]
    const float* gamma    = (const float*)d_in[4];   // [1000]
    const float* beta     = (const float*)d_in[5];   // [1000]
    const float* Wm       = (const float*)d_in[6];   // [1000][4]
    const float* bm       = (const float*)d_in[7];   // [4]
    float* out = (float*)d_out;

    uint8_t* ws = (uint8_t*)d_ws;
    unsigned short* feat_p = (unsigned short*)ws;                 //  5,767,168 B
    unsigned short* w1t    = (unsigned short*)(ws + 5767168);     //    720,896 B
    unsigned short* xwt    = (unsigned short*)(ws + 6488064);     // 16,777,216 B
    float*          h1     = (float*)(ws + 23265280);             // 33,554,432 B (total ~57 MB)

    k_cvt_feat<<<(NN * IN_PAD + 255) / 256, 256, 0, stream>>>(features, feat_p);
    k_cvt_w1t<<<(HID_PAD * IN_PAD + 255) / 256, 256, 0, stream>>>(W1, w1t);

    // GEMM1: xwt[1024][8192] = w1t[1024][352] * feat_p[8192][352]^T   (bf16 out)
    k_gemm_bf<<<(HID_PAD / 128) * (NN / 128), 256, 0, stream>>>(
        w1t, feat_p, xwt, HID_PAD, NN, IN_PAD);

    // GEMM2 fused: h1[8192][1024] = relu(adj * xwt^T + b1)  (fp32 adj converted in-kernel)
    k_gemm2_fused<<<(NN / 128) * (HID_PAD / 128), 256, 0, stream>>>(adj, xwt, h1, b1);

    k_ln_head<<<NN, 256, 0, stream>>>(h1, gamma, beta, Wm, bm, out);
}